// Round 1
// baseline (164.910 us; speedup 1.0000x reference)
//
#include <hip/hip_runtime.h>
#include <math.h>

#define N_VEC 65536
#define D 64
#define K 1024
#define VQ_EPS 1e-10f

typedef __attribute__((ext_vector_type(8))) short s16x8;   // 8 bf16 = 4 VGPR
typedef __attribute__((ext_vector_type(4))) float f32x4;   // MFMA acc

#define MFMA(a, b, c) __builtin_amdgcn_mfma_f32_16x16x32_bf16((a), (b), (c), 0, 0, 0)

__device__ __forceinline__ unsigned short bf16_rne(float f) {
    unsigned u = __float_as_uint(f);
    u += 0x7fff + ((u >> 16) & 1);
    return (unsigned short)(u >> 16);
}
__device__ __forceinline__ float bf16_f32(unsigned short h) {
    return __uint_as_float(((unsigned)h) << 16);
}

// ---------------------------------------------------------------------------
// Kernel A: pack embeddings into MFMA-fragment order (unchanged layout).
// Chunk id = ct*16 + g*4 + bg (bg: 0=hi k0-31, 1=hi k32-63, 2=lo k0-31,
// 3=lo k32-63). Slot q*16+c in a chunk = 16 B = 8 bf16 of code g*16+c.
// Changes vs prev: enorm stores -0.5*||e||^2 (pre-negated for acc init),
// and zeroes K+1 ints (counts[K] doubles as the vq completion counter).
// ---------------------------------------------------------------------------
__global__ void pack_e_kernel(const float* __restrict__ emb,
                              uint4* __restrict__ ep4,
                              float* __restrict__ enorm,
                              int* __restrict__ counts) {
    int gid = blockIdx.x * 256 + threadIdx.x;      // 0..4095
    int code = gid >> 2, tq = gid & 3;             // tq: k-quarter (16 elems)
    const float* row = emb + (size_t)code * D + tq * 16;
    unsigned int hi[8], lo[8];
    float nrm = 0.f;
#pragma unroll
    for (int i = 0; i < 4; ++i) {
        float4 v = *reinterpret_cast<const float4*>(row + i * 4);
        nrm += v.x * v.x + v.y * v.y + v.z * v.z + v.w * v.w;
        float f[4] = {v.x, v.y, v.z, v.w};
        unsigned short hh[4], ll[4];
#pragma unroll
        for (int j = 0; j < 4; ++j) {
            hh[j] = bf16_rne(f[j]);
            ll[j] = bf16_rne(f[j] - bf16_f32(hh[j]));
        }
        hi[i * 2 + 0] = (unsigned)hh[0] | ((unsigned)hh[1] << 16);
        hi[i * 2 + 1] = (unsigned)hh[2] | ((unsigned)hh[3] << 16);
        lo[i * 2 + 0] = (unsigned)ll[0] | ((unsigned)ll[1] << 16);
        lo[i * 2 + 1] = (unsigned)ll[2] | ((unsigned)ll[3] << 16);
    }
    const int ct = code >> 6, g = (code >> 4) & 3, c = code & 15;
#pragma unroll
    for (int h = 0; h < 2; ++h) {
        int gran = 2 * tq + h;               // 0..7
        int bg = gran >> 2, q = gran & 3;
        ep4[(size_t)(ct * 16 + g * 4 + bg) * 64 + q * 16 + c] =
            make_uint4(hi[h * 4], hi[h * 4 + 1], hi[h * 4 + 2], hi[h * 4 + 3]);
        int granl = 8 + gran;                // lo: bg 2..3
        bg = granl >> 2; q = granl & 3;
        ep4[(size_t)(ct * 16 + g * 4 + bg) * 64 + q * 16 + c] =
            make_uint4(lo[h * 4], lo[h * 4 + 1], lo[h * 4 + 2], lo[h * 4 + 3]);
    }
    nrm += __shfl_xor(nrm, 1, 64);
    nrm += __shfl_xor(nrm, 2, 64);
    if (tq == 0) enorm[code] = -0.5f * nrm;        // pre-negated half-norm
    if (gid <= K) counts[gid] = 0;                 // counts[K] = completion ctr
}

// ---------------------------------------------------------------------------
// Kernel B: barrier-free MFMA VQ.
//  - No LDS staging, no main-loop __syncthreads. B fragments are loaded
//    global->VGPR straight from the fragment-ordered ep4 (256 KB, resident
//    in every XCD's 4 MB L2). One-group register prefetch (Bc/Bn) hides
//    L2 latency inside each wave; waves are fully independent.
//  - Each wave owns 32 vectors (2 A-sets of 16) so every B load feeds
//    12 MFMAs: total L2 B-traffic = 2048 waves * 256 KB = 536 MB (~15.5 us
//    at the 34.5 TB/s L2 ceiling), vs 16 barriers/block in the old design.
//  - Numerics identical to previous verified kernel: score = dot - enc/2
//    via 6-MFMA bf16 hi/lo, acc init = -enc/2, strict-> argmax, ascending
//    group order => first-occurrence tie behavior preserved.
// C-layout: col(code)=lane&15, row(vec)=(lane>>4)*4+reg (m89-verified).
//  - Perplexity folded in: last block to finish (device atomic counter)
//    computes it from counts via agent-scope atomic loads.
// ---------------------------------------------------------------------------
__global__ void __launch_bounds__(256, 2)
vq_kernel(const float* __restrict__ x,
          const float* __restrict__ emb,
          const uint4* __restrict__ ep4,
          const float* __restrict__ enormp,   // holds -0.5*||e||^2
          int* __restrict__ counts,           // K+1 ints; [K] = completion ctr
          float* __restrict__ out) {
    __shared__ int   bks[128];
    __shared__ float ws[4];
    __shared__ int   amLast;

    const int t    = threadIdx.x;
    const int w    = t >> 6;
    const int lane = t & 63;
    const int q    = lane >> 4;
    const int c    = lane & 15;
    const int vb   = blockIdx.x * 128 + w * 32;

    // ---- A-frags: 32 vectors/wave (2 sets of 16), bf16 hi/lo ----
    s16x8 Ah[2][2], Al[2][2];
#pragma unroll
    for (int s = 0; s < 2; ++s)
#pragma unroll
        for (int h = 0; h < 2; ++h) {
            const float* xr = x + (size_t)(vb + s * 16 + c) * D + h * 32 + q * 8;
            float4 u0 = *reinterpret_cast<const float4*>(xr);
            float4 u1 = *reinterpret_cast<const float4*>(xr + 4);
            float f[8] = {u0.x, u0.y, u0.z, u0.w, u1.x, u1.y, u1.z, u1.w};
            s16x8 hiv, lov;
#pragma unroll
            for (int j = 0; j < 8; ++j) {
                unsigned short hb = bf16_rne(f[j]);
                hiv[j] = (short)hb;
                lov[j] = (short)bf16_rne(f[j] - bf16_f32(hb));
            }
            Ah[s][h] = hiv;
            Al[s][h] = lov;
        }

    float best[2][4];
    int   bk[2][4];
#pragma unroll
    for (int s = 0; s < 2; ++s)
#pragma unroll
        for (int r = 0; r < 4; ++r) { best[s][r] = -3.4e38f; bk[s][r] = 0; }

    // ---- main loop: 64 groups of 16 codes, 1-group register prefetch ----
    s16x8 Bc0, Bc1, Bc2, Bc3, Bn0, Bn1, Bn2, Bn3;
    float e2c, e2n;

#define LOADB(G, B0, B1, B2, B3, E2)                                          \
    {                                                                         \
        const uint4* bp = ep4 + ((size_t)(G) * 4) * 64 + lane;                \
        B0 = *reinterpret_cast<const s16x8*>(bp);                             \
        B1 = *reinterpret_cast<const s16x8*>(bp + 64);                        \
        B2 = *reinterpret_cast<const s16x8*>(bp + 128);                       \
        B3 = *reinterpret_cast<const s16x8*>(bp + 192);                       \
        E2 = enormp[(G) * 16 + c];                                            \
    }

#define BODY(G, B0, B1, B2, B3, E2)                                           \
    {                                                                         \
        const int codeG = (G) * 16 + c;                                       \
        _Pragma("unroll")                                                     \
        for (int s = 0; s < 2; ++s) {                                         \
            f32x4 acc = (f32x4){E2, E2, E2, E2};                              \
            acc = MFMA(Ah[s][0], B0, acc);                                    \
            acc = MFMA(Ah[s][1], B1, acc);                                    \
            acc = MFMA(Ah[s][0], B2, acc);                                    \
            acc = MFMA(Ah[s][1], B3, acc);                                    \
            acc = MFMA(Al[s][0], B0, acc);                                    \
            acc = MFMA(Al[s][1], B1, acc);                                    \
            _Pragma("unroll")                                                 \
            for (int r = 0; r < 4; ++r)                                       \
                if (acc[r] > best[s][r]) { best[s][r] = acc[r]; bk[s][r] = codeG; } \
        }                                                                     \
    }

    LOADB(0, Bc0, Bc1, Bc2, Bc3, e2c)
#pragma unroll 1
    for (int G = 0; G < 64; G += 2) {
        LOADB(G + 1, Bn0, Bn1, Bn2, Bn3, e2n)      // prefetch odd group
        BODY(G, Bc0, Bc1, Bc2, Bc3, e2c)           // compute even group
        const int Gp = (G + 2 < 64) ? (G + 2) : 63;
        LOADB(Gp, Bc0, Bc1, Bc2, Bc3, e2c)         // prefetch next even
        BODY(G + 1, Bn0, Bn1, Bn2, Bn3, e2n)       // compute odd group
    }
#undef LOADB
#undef BODY

    // ---- reduce over the 16 code-columns (max score; tie -> smaller idx) ----
#pragma unroll
    for (int m = 1; m <= 8; m <<= 1)
#pragma unroll
        for (int s = 0; s < 2; ++s)
#pragma unroll
            for (int r = 0; r < 4; ++r) {
                float ob = __shfl_xor(best[s][r], m, 64);
                int   ok = __shfl_xor(bk[s][r], m, 64);
                if (ob > best[s][r] || (ob == best[s][r] && ok < bk[s][r])) {
                    best[s][r] = ob; bk[s][r] = ok;
                }
            }
    if (c == 0) {
#pragma unroll
        for (int s = 0; s < 2; ++s)
#pragma unroll
            for (int r = 0; r < 4; ++r) {
                int lv = w * 32 + s * 16 + q * 4 + r;
                int kk = bk[s][r];
                bks[lv] = kk;
                atomicAdd(&counts[kk], 1);
            }
    }
    __syncthreads();   // bks ready; all this block's count atomics drained

    // ---- gather winning rows -> out (exact fp32) ----
#pragma unroll
    for (int half = 0; half < 2; ++half) {
        int vec = (t >> 2) + half * 64;            // 0..127
        int part = t & 3;
        int kk = bks[vec];
        const float4* src = reinterpret_cast<const float4*>(emb + (size_t)kk * D) + part * 4;
        float4* dst = reinterpret_cast<float4*>(out + (size_t)(blockIdx.x * 128 + vec) * D) + part * 4;
#pragma unroll
        for (int j = 0; j < 4; ++j) dst[j] = src[j];
    }

    // ---- last finishing block computes perplexity from counts ----
    __syncthreads();
    if (t == 0) {
        __threadfence();
        amLast = (atomicAdd(&counts[K], 1) == (int)gridDim.x - 1);
    }
    __syncthreads();
    if (amLast) {
        float s = 0.f;
#pragma unroll
        for (int i = 0; i < 4; ++i) {
            int cnt = __hip_atomic_load(&counts[t + i * 256], __ATOMIC_RELAXED,
                                        __HIP_MEMORY_SCOPE_AGENT);
            float p = (float)cnt * (1.0f / (float)N_VEC);
            s += p * logf(p + VQ_EPS);
        }
#pragma unroll
        for (int m = 1; m < 64; m <<= 1) s += __shfl_xor(s, m, 64);
        if (lane == 0) ws[w] = s;
        __syncthreads();
        if (t == 0) out[(size_t)N_VEC * D] = expf(-(ws[0] + ws[1] + ws[2] + ws[3]));
    }
}

// ---------------------------------------------------------------------------
extern "C" void kernel_launch(void* const* d_in, const int* in_sizes, int n_in,
                              void* d_out, int out_size, void* d_ws, size_t ws_size,
                              hipStream_t stream) {
    const float* x   = (const float*)d_in[0];   // [65536, 64] fp32
    const float* emb = (const float*)d_in[1];   // [1024, 64] fp32
    float* out = (float*)d_out;                 // 4194304 quantized + 1 perplexity

    uint4* ep     = (uint4*)d_ws;                                      // 256 KB packed
    float* enorm  = (float*)((char*)d_ws + (size_t)K * 128 * 2);       // 4 KB (-0.5*||e||^2)
    int*   counts = (int*)((char*)enorm + K * sizeof(float));          // K+1 ints

    pack_e_kernel<<<16, 256, 0, stream>>>(emb, ep, enorm, counts);
    vq_kernel<<<N_VEC / 128, 256, 0, stream>>>(x, emb, ep, enorm, counts, out);
}

// Round 2
// 157.604 us; speedup vs baseline: 1.0464x; 1.0464x over previous
//
#include <hip/hip_runtime.h>
#include <math.h>

#define N_VEC 65536
#define D 64
#define K 1024
#define VQ_EPS 1e-10f

typedef __attribute__((ext_vector_type(8))) short s16x8;   // 8 bf16 = 4 VGPR
typedef __attribute__((ext_vector_type(4))) float f32x4;   // MFMA acc

#define MFMA(a, b, c) __builtin_amdgcn_mfma_f32_16x16x32_bf16((a), (b), (c), 0, 0, 0)

__device__ __forceinline__ unsigned short bf16_rne(float f) {
    unsigned u = __float_as_uint(f);
    u += 0x7fff + ((u >> 16) & 1);
    return (unsigned short)(u >> 16);
}
__device__ __forceinline__ float bf16_f32(unsigned short h) {
    return __uint_as_float(((unsigned)h) << 16);
}

// async global->LDS DMA, 16 B per lane; LDS dest = wave-uniform base + lane*16
__device__ __forceinline__ void async_load16(const void* g, void* lds_generic) {
    __builtin_amdgcn_global_load_lds(
        (const __attribute__((address_space(1))) unsigned int*)g,
        (__attribute__((address_space(3))) unsigned int*)lds_generic, 16, 0, 0);
}

// ---------------------------------------------------------------------------
// Kernel A: pack embeddings into MFMA-fragment order (layout unchanged,
// verified). Chunk id = ct*16 + g*4 + bg (bg: 0=hi k0-31, 1=hi k32-63,
// 2=lo k0-31, 3=lo k32-63). Slot q*16+c in a chunk = 16 B = 8 bf16 of code
// g*16+c. enorm stores -0.5*||e||^2; counts[K] doubles as completion ctr.
// ---------------------------------------------------------------------------
__global__ void pack_e_kernel(const float* __restrict__ emb,
                              uint4* __restrict__ ep4,
                              float* __restrict__ enorm,
                              int* __restrict__ counts) {
    int gid = blockIdx.x * 256 + threadIdx.x;      // 0..4095
    int code = gid >> 2, tq = gid & 3;             // tq: k-quarter (16 elems)
    const float* row = emb + (size_t)code * D + tq * 16;
    unsigned int hi[8], lo[8];
    float nrm = 0.f;
#pragma unroll
    for (int i = 0; i < 4; ++i) {
        float4 v = *reinterpret_cast<const float4*>(row + i * 4);
        nrm += v.x * v.x + v.y * v.y + v.z * v.z + v.w * v.w;
        float f[4] = {v.x, v.y, v.z, v.w};
        unsigned short hh[4], ll[4];
#pragma unroll
        for (int j = 0; j < 4; ++j) {
            hh[j] = bf16_rne(f[j]);
            ll[j] = bf16_rne(f[j] - bf16_f32(hh[j]));
        }
        hi[i * 2 + 0] = (unsigned)hh[0] | ((unsigned)hh[1] << 16);
        hi[i * 2 + 1] = (unsigned)hh[2] | ((unsigned)hh[3] << 16);
        lo[i * 2 + 0] = (unsigned)ll[0] | ((unsigned)ll[1] << 16);
        lo[i * 2 + 1] = (unsigned)ll[2] | ((unsigned)ll[3] << 16);
    }
    const int ct = code >> 6, g = (code >> 4) & 3, c = code & 15;
#pragma unroll
    for (int h = 0; h < 2; ++h) {
        int gran = 2 * tq + h;               // 0..7
        int bg = gran >> 2, qq = gran & 3;
        ep4[(size_t)(ct * 16 + g * 4 + bg) * 64 + qq * 16 + c] =
            make_uint4(hi[h * 4], hi[h * 4 + 1], hi[h * 4 + 2], hi[h * 4 + 3]);
        int granl = 8 + gran;                // lo: bg 2..3
        bg = granl >> 2; qq = granl & 3;
        ep4[(size_t)(ct * 16 + g * 4 + bg) * 64 + qq * 16 + c] =
            make_uint4(lo[h * 4], lo[h * 4 + 1], lo[h * 4 + 2], lo[h * 4 + 3]);
    }
    nrm += __shfl_xor(nrm, 1, 64);
    nrm += __shfl_xor(nrm, 2, 64);
    if (tq == 0) enorm[code] = -0.5f * nrm;        // pre-negated half-norm
    if (gid <= K) counts[gid] = 0;                 // counts[K] = completion ctr
}

// ---------------------------------------------------------------------------
// Kernel B: resident-codebook MFMA VQ. 1 block/CU, 4 barriers total.
//  - Block = 256 vectors (grid 256 = #CUs). Wave owns 64 vectors as 4 A-sets
//    of 16 (64 VGPR); __launch_bounds__(256,1) -> up to 512 VGPR, no spill.
//  - Half the codebook (512 codes, 128 KB fragment-packed) staged in LDS via
//    global_load_lds; compute all 32 groups; restage other half; repeat.
//    Each ds_read_b128 quad feeds 24 MFMAs (4 sets x 6) -> LDS pipe ~10%,
//    L2 B-traffic 67 MB total (vs 536 MB in the failed R1 design).
//  - Latency hiding via ILP: 4 independent 6-deep MFMA chains + 1-group B
//    register prefetch. No main-loop barriers.
//  - Numerics identical to verified R0: score = dot - enc/2 (acc C-init),
//    strict > argmax, ascending scan = first-occurrence ties.
// C-layout: col(code)=lane&15, row(vec)=(lane>>4)*4+reg (m89-verified).
// ---------------------------------------------------------------------------
__global__ void __launch_bounds__(256, 1)
vq_kernel(const float* __restrict__ x,
          const float* __restrict__ emb,
          const uint4* __restrict__ ep4,
          const float* __restrict__ enormp,   // holds -0.5*||e||^2
          int* __restrict__ counts,           // K+1 ints; [K] = completion ctr
          float* __restrict__ out) {
    __shared__ __align__(16) unsigned short bt[128 * 512];   // 128 KB: half codebook
    __shared__ __align__(16) float en[K];                    // 4 KB norms
    __shared__ int   bks[256];
    __shared__ float ws[4];
    __shared__ int   amLast;

    const int t    = threadIdx.x;
    const int w    = t >> 6;
    const int lane = t & 63;
    const int q    = lane >> 4;
    const int c    = lane & 15;
    const int vbase = blockIdx.x * 256 + w * 64;

// stage one half (128 chunks x 1 KB) -> bt; wave w takes chunks w, w+4, ...
#define STAGE(halfIdx)                                                        \
    {                                                                         \
        const char* gsrc = (const char*)ep4 + (size_t)(halfIdx) * 131072      \
                           + (size_t)w * 1024 + (size_t)lane * 16;            \
        char* ldst = (char*)bt + w * 1024;                                    \
        _Pragma("unroll") for (int i = 0; i < 32; ++i)                        \
            async_load16(gsrc + (size_t)i * 4096, ldst + i * 4096);           \
    }

    // ---- issue half-0 stage + all norms -> LDS (DMA, zero VGPR) ----
    STAGE(0)
    async_load16((const char*)enormp + w * 1024 + (size_t)lane * 16,
                 (char*)en + w * 1024);

    // ---- A-frags: 64 vectors/wave (4 sets of 16), bf16 hi/lo (64 VGPR) ----
    s16x8 Ah[4][2], Al[4][2];
#pragma unroll
    for (int s = 0; s < 4; ++s)
#pragma unroll
        for (int h = 0; h < 2; ++h) {
            const float* xr = x + (size_t)(vbase + s * 16 + c) * D + h * 32 + q * 8;
            float4 u0 = *reinterpret_cast<const float4*>(xr);
            float4 u1 = *reinterpret_cast<const float4*>(xr + 4);
            float f[8] = {u0.x, u0.y, u0.z, u0.w, u1.x, u1.y, u1.z, u1.w};
            s16x8 hiv, lov;
#pragma unroll
            for (int j = 0; j < 8; ++j) {
                unsigned short hb = bf16_rne(f[j]);
                hiv[j] = (short)hb;
                lov[j] = (short)bf16_rne(f[j] - bf16_f32(hb));
            }
            Ah[s][h] = hiv;
            Al[s][h] = lov;
        }

    float best[4][4];
    int   bk[4][4];
#pragma unroll
    for (int s = 0; s < 4; ++s)
#pragma unroll
        for (int r = 0; r < 4; ++r) { best[s][r] = -3.4e38f; bk[s][r] = 0; }

    s16x8 Bc0, Bc1, Bc2, Bc3, Bn0, Bn1, Bn2, Bn3;
    float e2c, e2n;

// group G (local 0..31) uses chunks G*4..G*4+3 (bg order: hiK0,hiK1,loK0,loK1)
#define LOADB(G, B0, B1, B2, B3, E2)                                          \
    {                                                                         \
        const unsigned short* bp = bt + (size_t)(G) * 2048 + lane * 8;        \
        B0 = *reinterpret_cast<const s16x8*>(bp);                             \
        B1 = *reinterpret_cast<const s16x8*>(bp + 512);                       \
        B2 = *reinterpret_cast<const s16x8*>(bp + 1024);                      \
        B3 = *reinterpret_cast<const s16x8*>(bp + 1536);                      \
        E2 = en[cbase + (G) * 16 + c];                                        \
    }

#define BODY(G, B0, B1, B2, B3, E2)                                           \
    {                                                                         \
        const int codeG = cbase + (G) * 16 + c;                               \
        _Pragma("unroll")                                                     \
        for (int s = 0; s < 4; ++s) {                                         \
            f32x4 acc = (f32x4){E2, E2, E2, E2};                              \
            acc = MFMA(Ah[s][0], B0, acc);                                    \
            acc = MFMA(Ah[s][1], B1, acc);                                    \
            acc = MFMA(Ah[s][0], B2, acc);                                    \
            acc = MFMA(Ah[s][1], B3, acc);                                    \
            acc = MFMA(Al[s][0], B0, acc);                                    \
            acc = MFMA(Al[s][1], B1, acc);                                    \
            _Pragma("unroll")                                                 \
            for (int r = 0; r < 4; ++r)                                       \
                if (acc[r] > best[s][r]) { best[s][r] = acc[r]; bk[s][r] = codeG; } \
        }                                                                     \
    }

#define RUN_HALF                                                              \
    {                                                                         \
        LOADB(0, Bc0, Bc1, Bc2, Bc3, e2c)                                     \
        _Pragma("unroll 1")                                                   \
        for (int G = 0; G < 32; G += 2) {                                     \
            LOADB(G + 1, Bn0, Bn1, Bn2, Bn3, e2n)                             \
            BODY(G, Bc0, Bc1, Bc2, Bc3, e2c)                                  \
            const int Gp = (G + 2 < 32) ? (G + 2) : 31;                       \
            LOADB(Gp, Bc0, Bc1, Bc2, Bc3, e2c)                                \
            BODY(G + 1, Bn0, Bn1, Bn2, Bn3, e2n)                              \
        }                                                                     \
    }

    __syncthreads();          // half-0 tile + norms resident
    {
        const int cbase = 0;
        RUN_HALF
    }
    __syncthreads();          // everyone done reading bt
    STAGE(1)
    __syncthreads();          // half-1 tile resident
    {
        const int cbase = 512;
        RUN_HALF
    }
#undef STAGE
#undef LOADB
#undef BODY
#undef RUN_HALF

    // ---- reduce over the 16 code-columns (max score; tie -> smaller idx) ----
#pragma unroll
    for (int m = 1; m <= 8; m <<= 1)
#pragma unroll
        for (int s = 0; s < 4; ++s)
#pragma unroll
            for (int r = 0; r < 4; ++r) {
                float ob = __shfl_xor(best[s][r], m, 64);
                int   ok = __shfl_xor(bk[s][r], m, 64);
                if (ob > best[s][r] || (ob == best[s][r] && ok < bk[s][r])) {
                    best[s][r] = ob; bk[s][r] = ok;
                }
            }
    if (c == 0) {
#pragma unroll
        for (int s = 0; s < 4; ++s)
#pragma unroll
            for (int r = 0; r < 4; ++r) {
                int lv = w * 64 + s * 16 + q * 4 + r;
                int kk = bk[s][r];
                bks[lv] = kk;
                atomicAdd(&counts[kk], 1);
            }
    }
    __syncthreads();   // bks ready; this block's count atomics issued

    // ---- gather winning rows -> out (exact fp32) ----
#pragma unroll
    for (int rep = 0; rep < 4; ++rep) {
        int vec = (t >> 2) + rep * 64;             // 0..255
        int part = t & 3;
        int kk = bks[vec];
        const float4* src = reinterpret_cast<const float4*>(emb + (size_t)kk * D) + part * 4;
        float4* dst = reinterpret_cast<float4*>(out + (size_t)(blockIdx.x * 256 + vec) * D) + part * 4;
#pragma unroll
        for (int j = 0; j < 4; ++j) dst[j] = src[j];
    }

    // ---- last finishing block computes perplexity from counts ----
    __syncthreads();
    if (t == 0) {
        __threadfence();
        amLast = (atomicAdd(&counts[K], 1) == (int)gridDim.x - 1);
    }
    __syncthreads();
    if (amLast) {
        float s = 0.f;
#pragma unroll
        for (int i = 0; i < 4; ++i) {
            int cnt = __hip_atomic_load(&counts[t + i * 256], __ATOMIC_RELAXED,
                                        __HIP_MEMORY_SCOPE_AGENT);
            float p = (float)cnt * (1.0f / (float)N_VEC);
            s += p * logf(p + VQ_EPS);
        }
#pragma unroll
        for (int m = 1; m < 64; m <<= 1) s += __shfl_xor(s, m, 64);
        if (lane == 0) ws[w] = s;
        __syncthreads();
        if (t == 0) out[(size_t)N_VEC * D] = expf(-(ws[0] + ws[1] + ws[2] + ws[3]));
    }
}

// ---------------------------------------------------------------------------
extern "C" void kernel_launch(void* const* d_in, const int* in_sizes, int n_in,
                              void* d_out, int out_size, void* d_ws, size_t ws_size,
                              hipStream_t stream) {
    const float* x   = (const float*)d_in[0];   // [65536, 64] fp32
    const float* emb = (const float*)d_in[1];   // [1024, 64] fp32
    float* out = (float*)d_out;                 // 4194304 quantized + 1 perplexity

    uint4* ep     = (uint4*)d_ws;                                      // 256 KB packed
    float* enorm  = (float*)((char*)d_ws + (size_t)K * 128 * 2);       // 4 KB (-0.5*||e||^2)
    int*   counts = (int*)((char*)enorm + K * sizeof(float));          // K+1 ints

    pack_e_kernel<<<16, 256, 0, stream>>>(emb, ep, enorm, counts);
    vq_kernel<<<N_VEC / 256, 256, 0, stream>>>(x, emb, ep, enorm, counts, out);
}

// Round 3
// 155.716 us; speedup vs baseline: 1.0590x; 1.0121x over previous
//
#include <hip/hip_runtime.h>
#include <math.h>

#define N_VEC 65536
#define D 64
#define K 1024
#define VQ_EPS 1e-10f

typedef __attribute__((ext_vector_type(8))) short s16x8;   // 8 bf16 = 4 VGPR
typedef __attribute__((ext_vector_type(4))) float f32x4;   // MFMA acc

#define MFMA(a, b, c) __builtin_amdgcn_mfma_f32_16x16x32_bf16((a), (b), (c), 0, 0, 0)

__device__ __forceinline__ unsigned short bf16_rne(float f) {
    unsigned u = __float_as_uint(f);
    u += 0x7fff + ((u >> 16) & 1);
    return (unsigned short)(u >> 16);
}
__device__ __forceinline__ float bf16_f32(unsigned short h) {
    return __uint_as_float(((unsigned)h) << 16);
}

// async global->LDS DMA, 16 B per lane; LDS dest = wave-uniform base + lane*16
__device__ __forceinline__ void async_load16(const void* g, void* lds_generic) {
    __builtin_amdgcn_global_load_lds(
        (const __attribute__((address_space(1))) unsigned int*)g,
        (__attribute__((address_space(3))) unsigned int*)lds_generic, 16, 0, 0);
}

// ---------------------------------------------------------------------------
// Kernel A: pack embeddings into MFMA-fragment order (layout unchanged,
// verified). Chunk id = ct*16 + g*4 + bg (bg: 0=hi k0-31, 1=hi k32-63,
// 2=lo k0-31, 3=lo k32-63). Slot q*16+c in a chunk = 16 B = 8 bf16 of code
// g*16+c. enorm stores -0.5*||e||^2; counts[K] doubles as completion ctr.
// Widened to 64 blocks x 64 threads (same gid mapping) to cut latency.
// ---------------------------------------------------------------------------
__global__ void pack_e_kernel(const float* __restrict__ emb,
                              uint4* __restrict__ ep4,
                              float* __restrict__ enorm,
                              int* __restrict__ counts) {
    int gid = blockIdx.x * 64 + threadIdx.x;       // 0..4095
    int code = gid >> 2, tq = gid & 3;             // tq: k-quarter (16 elems)
    const float* row = emb + (size_t)code * D + tq * 16;
    unsigned int hi[8], lo[8];
    float nrm = 0.f;
#pragma unroll
    for (int i = 0; i < 4; ++i) {
        float4 v = *reinterpret_cast<const float4*>(row + i * 4);
        nrm += v.x * v.x + v.y * v.y + v.z * v.z + v.w * v.w;
        float f[4] = {v.x, v.y, v.z, v.w};
        unsigned short hh[4], ll[4];
#pragma unroll
        for (int j = 0; j < 4; ++j) {
            hh[j] = bf16_rne(f[j]);
            ll[j] = bf16_rne(f[j] - bf16_f32(hh[j]));
        }
        hi[i * 2 + 0] = (unsigned)hh[0] | ((unsigned)hh[1] << 16);
        hi[i * 2 + 1] = (unsigned)hh[2] | ((unsigned)hh[3] << 16);
        lo[i * 2 + 0] = (unsigned)ll[0] | ((unsigned)ll[1] << 16);
        lo[i * 2 + 1] = (unsigned)ll[2] | ((unsigned)ll[3] << 16);
    }
    const int ct = code >> 6, g = (code >> 4) & 3, c = code & 15;
#pragma unroll
    for (int h = 0; h < 2; ++h) {
        int gran = 2 * tq + h;               // 0..7
        int bg = gran >> 2, qq = gran & 3;
        ep4[(size_t)(ct * 16 + g * 4 + bg) * 64 + qq * 16 + c] =
            make_uint4(hi[h * 4], hi[h * 4 + 1], hi[h * 4 + 2], hi[h * 4 + 3]);
        int granl = 8 + gran;                // lo: bg 2..3
        bg = granl >> 2; qq = granl & 3;
        ep4[(size_t)(ct * 16 + g * 4 + bg) * 64 + qq * 16 + c] =
            make_uint4(lo[h * 4], lo[h * 4 + 1], lo[h * 4 + 2], lo[h * 4 + 3]);
    }
    nrm += __shfl_xor(nrm, 1, 64);
    nrm += __shfl_xor(nrm, 2, 64);
    if (tq == 0) enorm[code] = -0.5f * nrm;        // pre-negated half-norm
    if (gid <= K) counts[gid] = 0;                 // counts[K] = completion ctr
}

// ---------------------------------------------------------------------------
// Kernel B: MFMA VQ, latency-first design (R2 post-mortem: the binding
// resource is in-flight independent MFMAs per SIMD, not bandwidth).
//  - 2 blocks/CU (grid 512, 256 thr, LDS 68.6 KB, launch_bounds(256,2)):
//    2 waves/SIMD + 2 independent barrier groups per CU.
//  - Wave owns 32 vectors (2 A-sets). Each group's 6-product hi/lo sum is
//    split into TWO 3-deep partial chains (p,q) per set -> 4 independent
//    chains/wave, hand-interleaved round-robin: dependency spacing =
//    4 pipe slots x 2 waves ~ 155 cyc >= dependent MFMA latency.
//  - B: 8-phase LDS double-buffer (2 x 32 KB eighth-codebook tiles) via
//    global_load_lds, DMA-next-during-compute, ONE barrier per phase.
//    Each ds_read quad feeds 12 MFMAs; L2 staging = 512 x 256 KB = 134 MB.
//  - score = dot - enc/2 = (p + q) merged with 4 VALU adds; strict > argmax,
//    ascending scan = first-occurrence ties.
// C-layout: col(code)=lane&15, row(vec)=(lane>>4)*4+reg (m89-verified).
// ---------------------------------------------------------------------------
__global__ void __launch_bounds__(256, 2)
vq_kernel(const float* __restrict__ x,
          const float* __restrict__ emb,
          const uint4* __restrict__ ep4,
          const float* __restrict__ enormp,   // holds -0.5*||e||^2
          int* __restrict__ counts,           // K+1 ints; [K] = completion ctr
          float* __restrict__ out) {
    __shared__ __align__(16) unsigned short bt[2][16384];   // 2 x 32 KB tiles
    __shared__ __align__(16) float en[K];                   // 4 KB norms
    __shared__ int   bks[128];
    __shared__ float ws[4];
    __shared__ int   amLast;

    const int t    = threadIdx.x;
    const int w    = t >> 6;
    const int lane = t & 63;
    const int q    = lane >> 4;
    const int c    = lane & 15;
    const int vb   = blockIdx.x * 128 + w * 32;

// stage tile (32 chunks x 1 KB); wave w takes chunks w, w+4, ... (8 each)
#define STAGE(tile, buf)                                                      \
    {                                                                         \
        const char* gsrc = (const char*)ep4 + (size_t)(tile) * 32768          \
                           + (size_t)w * 1024 + (size_t)lane * 16;            \
        char* ldst = (char*)(buf) + w * 1024;                                 \
        _Pragma("unroll") for (int i = 0; i < 8; ++i)                         \
            async_load16(gsrc + (size_t)i * 4096, ldst + i * 4096);           \
    }

    // ---- issue tile-0 stage + all norms -> LDS (DMA, zero staging VGPRs) ----
    STAGE(0, bt[0])
    async_load16((const char*)enormp + w * 1024 + (size_t)lane * 16,
                 (char*)en + w * 1024);

    // ---- A-frags: 32 vectors/wave (2 sets of 16), bf16 hi/lo (32 VGPR) ----
    s16x8 Ah[2][2], Al[2][2];
#pragma unroll
    for (int s = 0; s < 2; ++s)
#pragma unroll
        for (int h = 0; h < 2; ++h) {
            const float* xr = x + (size_t)(vb + s * 16 + c) * D + h * 32 + q * 8;
            float4 u0 = *reinterpret_cast<const float4*>(xr);
            float4 u1 = *reinterpret_cast<const float4*>(xr + 4);
            float f[8] = {u0.x, u0.y, u0.z, u0.w, u1.x, u1.y, u1.z, u1.w};
            s16x8 hiv, lov;
#pragma unroll
            for (int j = 0; j < 8; ++j) {
                unsigned short hb = bf16_rne(f[j]);
                hiv[j] = (short)hb;
                lov[j] = (short)bf16_rne(f[j] - bf16_f32(hb));
            }
            Ah[s][h] = hiv;
            Al[s][h] = lov;
        }

    float best[2][4];
    int   bk[2][4];
#pragma unroll
    for (int s = 0; s < 2; ++s)
#pragma unroll
        for (int r = 0; r < 4; ++r) { best[s][r] = -3.4e38f; bk[s][r] = 0; }

    s16x8 Bc0, Bc1, Bc2, Bc3, Bn0, Bn1, Bn2, Bn3;
    float e2c, e2n;

// group G (0..7 within tile): chunks G*4+bg; bg order hiK0,hiK1,loK0,loK1
#define LOADB(buf, G, B0, B1, B2, B3, E2, cb)                                 \
    {                                                                         \
        const unsigned short* bp = (buf) + (unsigned)(G) * 2048 + lane * 8;   \
        B0 = *reinterpret_cast<const s16x8*>(bp);                             \
        B1 = *reinterpret_cast<const s16x8*>(bp + 512);                       \
        B2 = *reinterpret_cast<const s16x8*>(bp + 1024);                      \
        B3 = *reinterpret_cast<const s16x8*>(bp + 1536);                      \
        E2 = en[(cb) + (G) * 16 + c];                                         \
    }

// 12 MFMAs as 4 independent 3-deep chains, round-robin interleaved.
// per set s: p = e2 + Ah0*B0 + Ah1*B1 + Ah0*B2 ; q = Ah1*B3 + Al0*B0 + Al1*B1
#define BODY(G, B0, B1, B2, B3, E2, cb)                                       \
    {                                                                         \
        const int codeG = (cb) + (G) * 16 + c;                                \
        f32x4 p0 = (f32x4){E2, E2, E2, E2};                                   \
        f32x4 p1 = (f32x4){E2, E2, E2, E2};                                   \
        f32x4 q0 = (f32x4){0.f, 0.f, 0.f, 0.f};                               \
        f32x4 q1 = (f32x4){0.f, 0.f, 0.f, 0.f};                               \
        p0 = MFMA(Ah[0][0], B0, p0);                                          \
        p1 = MFMA(Ah[1][0], B0, p1);                                          \
        q0 = MFMA(Ah[0][1], B3, q0);                                          \
        q1 = MFMA(Ah[1][1], B3, q1);                                          \
        p0 = MFMA(Ah[0][1], B1, p0);                                          \
        p1 = MFMA(Ah[1][1], B1, p1);                                          \
        q0 = MFMA(Al[0][0], B0, q0);                                          \
        q1 = MFMA(Al[1][0], B0, q1);                                          \
        p0 = MFMA(Ah[0][0], B2, p0);                                          \
        p1 = MFMA(Ah[1][0], B2, p1);                                          \
        q0 = MFMA(Al[0][1], B1, q0);                                          \
        q1 = MFMA(Al[1][1], B1, q1);                                          \
        _Pragma("unroll")                                                     \
        for (int r = 0; r < 4; ++r) {                                         \
            float v0 = p0[r] + q0[r];                                         \
            if (v0 > best[0][r]) { best[0][r] = v0; bk[0][r] = codeG; }       \
            float v1 = p1[r] + q1[r];                                         \
            if (v1 > best[1][r]) { best[1][r] = v1; bk[1][r] = codeG; }       \
        }                                                                     \
    }

    __syncthreads();          // tile 0 + norms resident
#pragma unroll 1
    for (int tl = 0; tl < 8; ++tl) {
        if (tl < 7) STAGE(tl + 1, bt[(tl + 1) & 1])   // DMA next during compute
        const unsigned short* buf = bt[tl & 1];
        const int cb = tl * 128;
        LOADB(buf, 0, Bc0, Bc1, Bc2, Bc3, e2c, cb)
#pragma unroll 1
        for (int G = 0; G < 8; G += 2) {
            LOADB(buf, G + 1, Bn0, Bn1, Bn2, Bn3, e2n, cb)
            BODY(G, Bc0, Bc1, Bc2, Bc3, e2c, cb)
            const int Gp = (G + 2 < 8) ? (G + 2) : 7;
            LOADB(buf, Gp, Bc0, Bc1, Bc2, Bc3, e2c, cb)
            BODY(G + 1, Bn0, Bn1, Bn2, Bn3, e2n, cb)
        }
        __syncthreads();      // my DMA(tl+1) drained; all done reading buf
    }
#undef STAGE
#undef LOADB
#undef BODY

    // ---- reduce over the 16 code-columns (max score; tie -> smaller idx) ----
#pragma unroll
    for (int m = 1; m <= 8; m <<= 1)
#pragma unroll
        for (int s = 0; s < 2; ++s)
#pragma unroll
            for (int r = 0; r < 4; ++r) {
                float ob = __shfl_xor(best[s][r], m, 64);
                int   ok = __shfl_xor(bk[s][r], m, 64);
                if (ob > best[s][r] || (ob == best[s][r] && ok < bk[s][r])) {
                    best[s][r] = ob; bk[s][r] = ok;
                }
            }
    if (c == 0) {
#pragma unroll
        for (int s = 0; s < 2; ++s)
#pragma unroll
            for (int r = 0; r < 4; ++r) {
                int lv = w * 32 + s * 16 + q * 4 + r;
                int kk = bk[s][r];
                bks[lv] = kk;
                atomicAdd(&counts[kk], 1);
            }
    }
    __syncthreads();   // bks ready; this block's count atomics issued

    // ---- gather winning rows -> out (exact fp32) ----
#pragma unroll
    for (int rep = 0; rep < 2; ++rep) {
        int vec = (t >> 2) + rep * 64;             // 0..127
        int part = t & 3;
        int kk = bks[vec];
        const float4* src = reinterpret_cast<const float4*>(emb + (size_t)kk * D) + part * 4;
        float4* dst = reinterpret_cast<float4*>(out + (size_t)(blockIdx.x * 128 + vec) * D) + part * 4;
#pragma unroll
        for (int j = 0; j < 4; ++j) dst[j] = src[j];
    }

    // ---- last finishing block computes perplexity from counts ----
    __syncthreads();
    if (t == 0) {
        __threadfence();
        amLast = (atomicAdd(&counts[K], 1) == (int)gridDim.x - 1);
    }
    __syncthreads();
    if (amLast) {
        float s = 0.f;
#pragma unroll
        for (int i = 0; i < 4; ++i) {
            int cnt = __hip_atomic_load(&counts[t + i * 256], __ATOMIC_RELAXED,
                                        __HIP_MEMORY_SCOPE_AGENT);
            float p = (float)cnt * (1.0f / (float)N_VEC);
            s += p * logf(p + VQ_EPS);
        }
#pragma unroll
        for (int m = 1; m < 64; m <<= 1) s += __shfl_xor(s, m, 64);
        if (lane == 0) ws[w] = s;
        __syncthreads();
        if (t == 0) out[(size_t)N_VEC * D] = expf(-(ws[0] + ws[1] + ws[2] + ws[3]));
    }
}

// ---------------------------------------------------------------------------
extern "C" void kernel_launch(void* const* d_in, const int* in_sizes, int n_in,
                              void* d_out, int out_size, void* d_ws, size_t ws_size,
                              hipStream_t stream) {
    const float* x   = (const float*)d_in[0];   // [65536, 64] fp32
    const float* emb = (const float*)d_in[1];   // [1024, 64] fp32
    float* out = (float*)d_out;                 // 4194304 quantized + 1 perplexity

    uint4* ep     = (uint4*)d_ws;                                      // 256 KB packed
    float* enorm  = (float*)((char*)d_ws + (size_t)K * 128 * 2);       // 4 KB (-0.5*||e||^2)
    int*   counts = (int*)((char*)enorm + K * sizeof(float));          // K+1 ints

    pack_e_kernel<<<64, 64, 0, stream>>>(emb, ep, enorm, counts);
    vq_kernel<<<N_VEC / 128, 256, 0, stream>>>(x, emb, ep, enorm, counts, out);
}